// Round 2
// baseline (130.853 us; speedup 1.0000x reference)
//
#include <hip/hip_runtime.h>

// B=2, C=3, H=W=1024, fp32. History: R11 139.6us; R12 (interior/border split,
// pixel-space coords, ks==0 skip) 123.2us bench, 56us/dispatch: VALU 65%,
// conflicts 1.48e7cy (58k/CU = 43% of runtime), occ 68%, VGPR 24.
// R13: LDS record packing + value-path FMA.
//  - (x0,x1,x2,tx) packed in one float4 record (16B aligned); ty scalar plane.
//    Corner-set = 4x ds_read_b128 + 2x ds_read2_b32 off 2 addresses (was ~10
//    narrow reads + 5 addr adds). Same 20 words; wide reads amortize max-bank
//    serialization (256 words/instr vs 64) => conflict cycles should drop ~35%.
//  - explicit fmaf on the VALUE path only (color bilinear + accum). Positions,
//    weights, tangent bilinear stay contract-off => trajectories bit-identical,
//    absmax stays at the chaos floor 0.00390625.
//  - final step hoisted out of the march loop: when ks[3]==0 (sigma=6) the
//    uniform skip now elides mkcorn AND the 16-word q-load structurally.
constexpr int Bb = 2, Cc = 3, Hh = 1024, Ww = 1024;
constexpr int HWp = Hh * Ww;
constexpr int N_STEPS = 4;
constexpr int TS = 16;                  // pixels per tile side
constexpr int HALO = 6;                 // >= max drift 4.5 + margin
constexpr int TD = TS + 2 * HALO;       // 28
constexpr int TSTR = TD + 1;            // 29 records/row: bank rot 20/row for
                                        // float4 records, 26/row for scalars

struct Corn { int o00, o01, o10, o11; float wx, wy, omx, omy; };

// Interior: pixel-space positions, never clamps (drift bound |dp|<=4.5px).
__device__ __forceinline__ Corn mkcorn_int(float px, float py, int ox, int oy) {
#pragma clang fp contract(off)
    float fx = px - 0.5f;
    float fy = py - 0.5f;
    float fx0 = floorf(fx), fy0 = floorf(fy);
    Corn c;
    c.wx = fx - fx0;  c.wy = fy - fy0;
    c.omx = 1.0f - c.wx;  c.omy = 1.0f - c.wy;
    int o = ((int)fy0 - oy) * TSTR + ((int)fx0 - ox);
    c.o00 = o;        c.o01 = o + 1;
    c.o10 = o + TSTR; c.o11 = o + TSTR + 1;
    return c;
}

// Border: full clamp logic, arithmetic identical to R12.
__device__ __forceinline__ Corn mkcorn_bor(float px, float py, int ox, int oy) {
#pragma clang fp contract(off)
    float fx = px - 0.5f;
    float fy = py - 0.5f;
    float fx0 = floorf(fx), fy0 = floorf(fy);
    Corn c;
    c.wx = fx - fx0;  c.wy = fy - fy0;
    c.omx = 1.0f - c.wx;  c.omy = 1.0f - c.wy;
    int x0 = (int)fx0, y0 = (int)fy0;
    int x0i = min(max(x0, 0), Ww - 1);
    int x1i = min(x0i + 1, Ww - 1);
    int y0i = min(max(y0, 0), Hh - 1);
    int y1i = min(y0i + 1, Hh - 1);
    int lx0 = x0i - ox, lx1 = x1i - ox;
    int ly0 = y0i - oy, ly1 = y1i - oy;
    c.o00 = ly0 * TSTR + lx0;  c.o01 = ly0 * TSTR + lx1;
    c.o10 = ly1 * TSTR + lx0;  c.o11 = ly1 * TSTR + lx1;
    return c;
}

template <bool BORDER>
__device__ __forceinline__ void run_tile(
    const float* __restrict__ x, const float* __restrict__ tg,
    const float* __restrict__ sg, float* __restrict__ out,
    float4 (&colS)[TD * TSTR], float (&tyS)[TD * TSTR])
{
#pragma clang fp contract(off)
    const int tx0 = blockIdx.x * TS, ty0 = blockIdx.y * TS;
    const int b = blockIdx.z;
    const int tid = threadIdx.x;          // 0..255

    const float* xp  = x  + (size_t)b * Cc * HWp;
    const float* txp = tg + (size_t)b * 2 * HWp;
    const float* typ = txp + HWp;
    const int ox = tx0 - HALO, oy = ty0 - HALO;

    // ---- uniform per-block kernel weights (overlap staging latency)
    float sig = sg[b];
    float half_width = 2.0f * sig;
    float two_sigma2 = (2.0f * sig) * sig;
    const float stepf = (float)(1.0 / 0.3333);
    float ks[N_STEPS];
#pragma unroll
    for (int it = 0; it < N_STEPS; ++it) {
        float r = ((float)it + 1.0f) * stepf;
        float k = expf(-(r * r) / two_sigma2);
        ks[it] = (r < half_width) ? k : 0.0f;
    }

    // ---- stage 28x28: (x0,x1,x2,tx) as float4 record + ty scalar
    for (int e = tid; e < TD * TD; e += 256) {
        int r = e / TD, cc = e - r * TD;
        int gy = oy + r, gx = ox + cc;
        if (BORDER) {
            gy = min(max(gy, 0), Hh - 1);
            gx = min(max(gx, 0), Ww - 1);
        }
        int g = gy * Ww + gx;
        float4 q;
        q.x = xp[g]; q.y = xp[g + HWp]; q.z = xp[g + 2 * HWp]; q.w = txp[g];
        colS[r * TSTR + cc] = q;
        tyS [r * TSTR + cc] = typ[g];
    }
    __syncthreads();

    // ---- per-pixel march, positions in PIXEL units (exact x1024 rescale)
    const int lx = tid & (TS - 1), ly = tid >> 4;
    const int j = tx0 + lx, i = ty0 + ly;
    const int ctr = (HALO + ly) * TSTR + (HALO + lx);

    const float psx = (float)j + 0.5f;
    const float psy = (float)i + 0.5f;

    const float4 ctrq = colS[ctr];        // x0,x1,x2,tx at center
    const float v0x = ctrq.w;
    const float v0y = tyS[ctr];

    float c1a = 0.f, c1b = 0.f, c1c = 0.f, s1 = 0.f;
    float c2a = 0.f, c2b = 0.f, c2c = 0.f, s2 = 0.f;

#pragma unroll
    for (int d = 0; d < 2; ++d) {
        float vx = d ? -v0x : v0x;
        float vy = d ? -v0y : v0y;
        float px = psx + vx;              // p0 = p_start + v0/tex (pixel units)
        float py = psy + vy;
        float a0 = 0.f, a1 = 0.f, a2 = 0.f, as = 0.f;

#pragma unroll
        for (int it = 0; it < N_STEPS - 1; ++it) {
            Corn c = BORDER ? mkcorn_bor(px, py, ox, oy)
                            : mkcorn_int(px, py, ox, oy);
            float4 q00 = colS[c.o00], q01 = colS[c.o01];
            float4 q10 = colS[c.o10], q11 = colS[c.o11];
            if (ks[it] != 0.0f) {         // block-uniform
                float w = ks[it];
                if (BORDER) {
                    bool inb = (px >= 0.0f) && (px < 1024.0f) &&
                               (py >= 0.0f) && (py < 1024.0f);
                    w = inb ? w : 0.0f;
                }
                // value path: explicit FMA (positions/weights untouched)
                float t0 = fmaf(q01.x, c.wx, q00.x * c.omx);
                float b0 = fmaf(q11.x, c.wx, q10.x * c.omx);
                a0 = fmaf(fmaf(b0, c.wy, t0 * c.omy), w, a0);
                float t1 = fmaf(q01.y, c.wx, q00.y * c.omx);
                float b1 = fmaf(q11.y, c.wx, q10.y * c.omx);
                a1 = fmaf(fmaf(b1, c.wy, t1 * c.omy), w, a1);
                float t2 = fmaf(q01.z, c.wx, q00.z * c.omx);
                float b2 = fmaf(q11.z, c.wx, q10.z * c.omx);
                a2 = fmaf(fmaf(b2, c.wy, t2 * c.omy), w, a2);
                as += w;
            }
            // tangent bilinear: contract-off, bit-identical trajectory
            float y00 = tyS[c.o00], y01 = tyS[c.o01];
            float y10 = tyS[c.o10], y11 = tyS[c.o11];
            float xt = q00.w * c.omx + q01.w * c.wx;
            float xb = q10.w * c.omx + q11.w * c.wx;
            float tfx = xt * c.omy + xb * c.wy;
            float yt = y00 * c.omx + y01 * c.wx;
            float yb = y10 * c.omx + y11 * c.wx;
            float tfy = yt * c.omy + yb * c.wy;
            float vt = (vx * tfx) + (vy * tfy);
            if (vt < 0.0f) { tfx = -tfx; tfy = -tfy; }
            px = px + tfx;
            py = py + tfy;
            vx = tfx; vy = tfy;
        }
        // final step: color only; skipped entirely (corner+loads) when ks==0
        if (ks[N_STEPS - 1] != 0.0f) {
            Corn c = BORDER ? mkcorn_bor(px, py, ox, oy)
                            : mkcorn_int(px, py, ox, oy);
            float w = ks[N_STEPS - 1];
            if (BORDER) {
                bool inb = (px >= 0.0f) && (px < 1024.0f) &&
                           (py >= 0.0f) && (py < 1024.0f);
                w = inb ? w : 0.0f;
            }
            float4 q00 = colS[c.o00], q01 = colS[c.o01];
            float4 q10 = colS[c.o10], q11 = colS[c.o11];
            float t0 = fmaf(q01.x, c.wx, q00.x * c.omx);
            float b0 = fmaf(q11.x, c.wx, q10.x * c.omx);
            a0 = fmaf(fmaf(b0, c.wy, t0 * c.omy), w, a0);
            float t1 = fmaf(q01.y, c.wx, q00.y * c.omx);
            float b1 = fmaf(q11.y, c.wx, q10.y * c.omx);
            a1 = fmaf(fmaf(b1, c.wy, t1 * c.omy), w, a1);
            float t2 = fmaf(q01.z, c.wx, q00.z * c.omx);
            float b2 = fmaf(q11.z, c.wx, q10.z * c.omx);
            a2 = fmaf(fmaf(b2, c.wy, t2 * c.omy), w, a2);
            as += w;
        }
        if (d == 0) { c1a = a0; c1b = a1; c1c = a2; s1 = as; }
        else        { c2a = a0; c2b = a1; c2c = a2; s2 = as; }
    }

    const int pix = i * Ww + j;
    float denom = (1.0f + s1) + s2;
    float* op = out + (size_t)b * Cc * HWp;
    op[pix]           = ((ctrq.x + c1a) + c2a) / denom;
    op[pix + HWp]     = ((ctrq.y + c1b) + c2b) / denom;
    op[pix + 2 * HWp] = ((ctrq.z + c1c) + c2c) / denom;
}

__global__ __launch_bounds__(256, 8) void flow_smooth_kernel(
    const float* __restrict__ x,
    const float* __restrict__ tg,
    const float* __restrict__ sg,
    float* __restrict__ out)
{
    __shared__ float4 colS[TD * TSTR];    // 12.7 KB
    __shared__ float  tyS [TD * TSTR];    // 3.2 KB
    const bool border = (blockIdx.x == 0) || (blockIdx.x == gridDim.x - 1) ||
                        (blockIdx.y == 0) || (blockIdx.y == gridDim.y - 1);
    if (border) run_tile<true >(x, tg, sg, out, colS, tyS);
    else        run_tile<false>(x, tg, sg, out, colS, tyS);
}

extern "C" void kernel_launch(void* const* d_in, const int* in_sizes, int n_in,
                              void* d_out, int out_size, void* d_ws, size_t ws_size,
                              hipStream_t stream) {
    const float* x = nullptr; const float* tg = nullptr; const float* sg = nullptr;
    for (int t = 0; t < n_in; ++t) {
        if (in_sizes[t] == Bb * Cc * HWp)      x  = (const float*)d_in[t];
        else if (in_sizes[t] == Bb * 2 * HWp)  tg = (const float*)d_in[t];
        else                                   sg = (const float*)d_in[t];
    }
    float* out = (float*)d_out;

    dim3 block(256, 1, 1);
    dim3 grid(Ww / TS, Hh / TS, Bb);   // 64 x 64 x 2 = 8192 blocks
    flow_smooth_kernel<<<grid, block, 0, stream>>>(x, tg, sg, out);
}

// Round 3
// 124.912 us; speedup vs baseline: 1.0476x; 1.0476x over previous
//
#include <hip/hip_runtime.h>

// B=2, C=3, H=W=1024, fp32. History: R11 139.6us; R12 (interior/border split,
// pixel-space coords) 56.1us/disp, conflicts 1.48e7, VALU 65%; R13 (float4
// record packing) REGRESSED to 62.2us/disp, conflicts 1.73e7 -- measured:
// b128 random-record gather is ~21% worse per word than scalar/read2 (4-word
// records alias into 8 bank-groups; no max-bank amortization on gfx950).
// R14: revert to scalar 5-plane LDS (R12's 1.23e5 cy/word conflict regime),
// KEEP the R13 VALU wins (fmaf value path, final-step hoist), and cut dead
// gather words: the last live step's tangent bilinear feeds only a
// zero-weight sample when ks[it+1]==0 (sigma=6 => ks[3]=0) -- uniform-guard
// skip removes 8 words + ~30 VALU per direction. 120 -> 104 words/thread.
// ks is a prefix (exp decays; r<half_width only shuts off) so a uniform
// break on ks[it]==0 is exact. Trajectory arithmetic stays contract-off
// bit-identical => absmax must remain exactly 0.00390625.
constexpr int Bb = 2, Cc = 3, Hh = 1024, Ww = 1024;
constexpr int HWp = Hh * Ww;
constexpr int N_STEPS = 4;
constexpr int TS = 16;                  // pixels per tile side
constexpr int HALO = 6;                 // >= max drift 4.5 + margin
constexpr int TD = TS + 2 * HALO;       // 28
constexpr int TSTR = TD + 1;            // 29 (odd stride: breaks bank patterns)

struct Corn { int o00, o01, o10, o11; float wx, wy, omx, omy; };

// Interior: pixel-space positions, never clamps (drift bound |dp|<=4.5px).
__device__ __forceinline__ Corn mkcorn_int(float px, float py, int ox, int oy) {
#pragma clang fp contract(off)
    float fx = px - 0.5f;
    float fy = py - 0.5f;
    float fx0 = floorf(fx), fy0 = floorf(fy);
    Corn c;
    c.wx = fx - fx0;  c.wy = fy - fy0;
    c.omx = 1.0f - c.wx;  c.omy = 1.0f - c.wy;
    int o = ((int)fy0 - oy) * TSTR + ((int)fx0 - ox);
    c.o00 = o;        c.o01 = o + 1;          // read2-mergeable pairs
    c.o10 = o + TSTR; c.o11 = o + TSTR + 1;
    return c;
}

// Border: full clamp logic, arithmetic identical to R12.
__device__ __forceinline__ Corn mkcorn_bor(float px, float py, int ox, int oy) {
#pragma clang fp contract(off)
    float fx = px - 0.5f;
    float fy = py - 0.5f;
    float fx0 = floorf(fx), fy0 = floorf(fy);
    Corn c;
    c.wx = fx - fx0;  c.wy = fy - fy0;
    c.omx = 1.0f - c.wx;  c.omy = 1.0f - c.wy;
    int x0 = (int)fx0, y0 = (int)fy0;
    int x0i = min(max(x0, 0), Ww - 1);
    int x1i = min(x0i + 1, Ww - 1);
    int y0i = min(max(y0, 0), Hh - 1);
    int y1i = min(y0i + 1, Hh - 1);
    int lx0 = x0i - ox, lx1 = x1i - ox;
    int ly0 = y0i - oy, ly1 = y1i - oy;
    c.o00 = ly0 * TSTR + lx0;  c.o01 = ly0 * TSTR + lx1;
    c.o10 = ly1 * TSTR + lx0;  c.o11 = ly1 * TSTR + lx1;
    return c;
}

template <bool BORDER>
__device__ __forceinline__ void run_tile(
    const float* __restrict__ x, const float* __restrict__ tg,
    const float* __restrict__ sg, float* __restrict__ out,
    float (&lds)[5][TD * TSTR])
{
#pragma clang fp contract(off)
    const int tx0 = blockIdx.x * TS, ty0 = blockIdx.y * TS;
    const int b = blockIdx.z;
    const int tid = threadIdx.x;          // 0..255

    const float* xp  = x  + (size_t)b * Cc * HWp;
    const float* txp = tg + (size_t)b * 2 * HWp;
    const float* planes[5] = { xp, xp + HWp, xp + 2 * HWp, txp, txp + HWp };
    const int ox = tx0 - HALO, oy = ty0 - HALO;

    // ---- uniform per-block kernel weights (overlap staging latency)
    float sig = sg[b];
    float half_width = 2.0f * sig;
    float two_sigma2 = (2.0f * sig) * sig;
    const float stepf = (float)(1.0 / 0.3333);
    float ks[N_STEPS];
#pragma unroll
    for (int it = 0; it < N_STEPS; ++it) {
        float r = ((float)it + 1.0f) * stepf;
        float k = expf(-(r * r) / two_sigma2);
        ks[it] = (r < half_width) ? k : 0.0f;
    }

    // ---- stage 28x28 x 5 scalar planes into LDS
    for (int e = tid; e < TD * TD; e += 256) {
        int r = e / TD, cc = e - r * TD;
        int gy = oy + r, gx = ox + cc;
        if (BORDER) {
            gy = min(max(gy, 0), Hh - 1);
            gx = min(max(gx, 0), Ww - 1);
        }
        int g = gy * Ww + gx;
#pragma unroll
        for (int pl = 0; pl < 5; ++pl)
            lds[pl][r * TSTR + cc] = planes[pl][g];
    }
    __syncthreads();

    // ---- per-pixel march, positions in PIXEL units (exact x1024 rescale)
    const int lx = tid & (TS - 1), ly = tid >> 4;
    const int j = tx0 + lx, i = ty0 + ly;
    const int ctr = (HALO + ly) * TSTR + (HALO + lx);

    const float psx = (float)j + 0.5f;
    const float psy = (float)i + 0.5f;

    const float v0x = lds[3][ctr];
    const float v0y = lds[4][ctr];

    float c1a = 0.f, c1b = 0.f, c1c = 0.f, s1 = 0.f;
    float c2a = 0.f, c2b = 0.f, c2c = 0.f, s2 = 0.f;

#pragma unroll
    for (int d = 0; d < 2; ++d) {
        float vx = d ? -v0x : v0x;
        float vy = d ? -v0y : v0y;
        float px = psx + vx;              // p0 = p_start + v0/tex (pixel units)
        float py = psy + vy;
        float a0 = 0.f, a1 = 0.f, a2 = 0.f, as = 0.f;

#pragma unroll
        for (int it = 0; it < N_STEPS; ++it) {
            if (ks[it] == 0.0f) break;    // uniform; ks nonzero is a prefix
            Corn c = BORDER ? mkcorn_bor(px, py, ox, oy)
                            : mkcorn_int(px, py, ox, oy);
            float w = ks[it];
            if (BORDER) {
                bool inb = (px >= 0.0f) && (px < 1024.0f) &&
                           (py >= 0.0f) && (py < 1024.0f);
                w = inb ? w : 0.0f;
            }
            // ---- color: product weights shared by 3 planes, fmaf tree.
            // (value path only -- trajectories not affected)
            float w00 = c.omx * c.omy, w01 = c.wx * c.omy;
            float w10 = c.omx * c.wy,  w11 = c.wx * c.wy;
            {
                float s0 = fmaf(w01, lds[0][c.o01], w00 * lds[0][c.o00]);
                s0 = fmaf(w10, lds[0][c.o10], s0);
                s0 = fmaf(w11, lds[0][c.o11], s0);
                a0 = fmaf(s0, w, a0);
                float s1v = fmaf(w01, lds[1][c.o01], w00 * lds[1][c.o00]);
                s1v = fmaf(w10, lds[1][c.o10], s1v);
                s1v = fmaf(w11, lds[1][c.o11], s1v);
                a1 = fmaf(s1v, w, a1);
                float s2v = fmaf(w01, lds[2][c.o01], w00 * lds[2][c.o00]);
                s2v = fmaf(w10, lds[2][c.o10], s2v);
                s2v = fmaf(w11, lds[2][c.o11], s2v);
                a2 = fmaf(s2v, w, a2);
            }
            as += w;
            // ---- tangent advance: only if the NEXT sample is live
            // (dead otherwise: its only consumer is a zero-weight color).
            if (it < N_STEPS - 1 && ks[it + 1] != 0.0f) {
                float x00 = lds[3][c.o00], x01 = lds[3][c.o01];
                float x10 = lds[3][c.o10], x11 = lds[3][c.o11];
                float y00 = lds[4][c.o00], y01 = lds[4][c.o01];
                float y10 = lds[4][c.o10], y11 = lds[4][c.o11];
                // contract-off, bit-identical to reference
                float xt = x00 * c.omx + x01 * c.wx;
                float xb = x10 * c.omx + x11 * c.wx;
                float tfx = xt * c.omy + xb * c.wy;
                float yt = y00 * c.omx + y01 * c.wx;
                float yb = y10 * c.omx + y11 * c.wx;
                float tfy = yt * c.omy + yb * c.wy;
                float vt = (vx * tfx) + (vy * tfy);
                if (vt < 0.0f) { tfx = -tfx; tfy = -tfy; }
                px = px + tfx;
                py = py + tfy;
                vx = tfx; vy = tfy;
            }
        }
        if (d == 0) { c1a = a0; c1b = a1; c1c = a2; s1 = as; }
        else        { c2a = a0; c2b = a1; c2c = a2; s2 = as; }
    }

    const int pix = i * Ww + j;
    float xc0 = lds[0][ctr], xc1 = lds[1][ctr], xc2 = lds[2][ctr];
    float denom = (1.0f + s1) + s2;
    float* op = out + (size_t)b * Cc * HWp;
    op[pix]           = ((xc0 + c1a) + c2a) / denom;
    op[pix + HWp]     = ((xc1 + c1b) + c2b) / denom;
    op[pix + 2 * HWp] = ((xc2 + c1c) + c2c) / denom;
}

__global__ __launch_bounds__(256, 8) void flow_smooth_kernel(
    const float* __restrict__ x,
    const float* __restrict__ tg,
    const float* __restrict__ sg,
    float* __restrict__ out)
{
    __shared__ float lds[5][TD * TSTR];   // 16.2 KB
    const bool border = (blockIdx.x == 0) || (blockIdx.x == gridDim.x - 1) ||
                        (blockIdx.y == 0) || (blockIdx.y == gridDim.y - 1);
    if (border) run_tile<true >(x, tg, sg, out, lds);
    else        run_tile<false>(x, tg, sg, out, lds);
}

extern "C" void kernel_launch(void* const* d_in, const int* in_sizes, int n_in,
                              void* d_out, int out_size, void* d_ws, size_t ws_size,
                              hipStream_t stream) {
    const float* x = nullptr; const float* tg = nullptr; const float* sg = nullptr;
    for (int t = 0; t < n_in; ++t) {
        if (in_sizes[t] == Bb * Cc * HWp)      x  = (const float*)d_in[t];
        else if (in_sizes[t] == Bb * 2 * HWp)  tg = (const float*)d_in[t];
        else                                   sg = (const float*)d_in[t];
    }
    float* out = (float*)d_out;

    dim3 block(256, 1, 1);
    dim3 grid(Ww / TS, Hh / TS, Bb);   // 64 x 64 x 2 = 8192 blocks
    flow_smooth_kernel<<<grid, block, 0, stream>>>(x, tg, sg, out);
}

// Round 4
// 123.248 us; speedup vs baseline: 1.0617x; 1.0135x over previous
//
#include <hip/hip_runtime.h>

// B=2, C=3, H=W=1024, fp32. History: R12 56.1us (interior/border split, pixel
// coords); R13 float4-packing REGRESSED (62.2us, b128 random gather ~21%
// worse/word); R14 53.7us (fmaf color, dead-load guards) -- but conflicts
// stayed EXACTLY 1.478e7 == R12: the ks-guards are VGPR conditions, so the
// backend IF-CONVERTS them (no s_cbranch) and the "dead" tangent/color loads
// still issue. ~40 words/thread of dead gather traffic survive.
// R15: (a) liveness count through readfirstlane -> SGPR -> real s_cbranch;
// march restructured as nested if(nlive>=k) blocks (ks-nonzero is a prefix:
// exp never 0, r<half_width monotone shuts off => exact). (b) manual
// interleave of the two independent direction chains (A=+v0, B=-v0) to double
// issue density on the serial mkcorn->loads->bilinear->advance chain (VGPR 28
// proves the compiler serialized them). Trajectory math contract-off,
// bit-identical => absmax must remain exactly 0.00390625.
constexpr int Bb = 2, Cc = 3, Hh = 1024, Ww = 1024;
constexpr int HWp = Hh * Ww;
constexpr int TS = 16;                  // pixels per tile side
constexpr int HALO = 6;                 // >= max drift 4.5 + margin
constexpr int TD = TS + 2 * HALO;       // 28
constexpr int TSTR = TD + 1;            // 29 (odd stride)

struct Corn { int o00, o01, o10, o11; float wx, wy, omx, omy; };

// Interior: pixel-space positions, never clamps (drift bound |dp|<=4.5px).
__device__ __forceinline__ Corn mkcorn_int(float px, float py, int ox, int oy) {
#pragma clang fp contract(off)
    float fx = px - 0.5f;
    float fy = py - 0.5f;
    float fx0 = floorf(fx), fy0 = floorf(fy);
    Corn c;
    c.wx = fx - fx0;  c.wy = fy - fy0;
    c.omx = 1.0f - c.wx;  c.omy = 1.0f - c.wy;
    int o = ((int)fy0 - oy) * TSTR + ((int)fx0 - ox);
    c.o00 = o;        c.o01 = o + 1;          // read2-mergeable pairs
    c.o10 = o + TSTR; c.o11 = o + TSTR + 1;
    return c;
}

// Border: full clamp logic, arithmetic identical to R12.
__device__ __forceinline__ Corn mkcorn_bor(float px, float py, int ox, int oy) {
#pragma clang fp contract(off)
    float fx = px - 0.5f;
    float fy = py - 0.5f;
    float fx0 = floorf(fx), fy0 = floorf(fy);
    Corn c;
    c.wx = fx - fx0;  c.wy = fy - fy0;
    c.omx = 1.0f - c.wx;  c.omy = 1.0f - c.wy;
    int x0 = (int)fx0, y0 = (int)fy0;
    int x0i = min(max(x0, 0), Ww - 1);
    int x1i = min(x0i + 1, Ww - 1);
    int y0i = min(max(y0, 0), Hh - 1);
    int y1i = min(y0i + 1, Hh - 1);
    int lx0 = x0i - ox, lx1 = x1i - ox;
    int ly0 = y0i - oy, ly1 = y1i - oy;
    c.o00 = ly0 * TSTR + lx0;  c.o01 = ly0 * TSTR + lx1;
    c.o10 = ly1 * TSTR + lx0;  c.o11 = ly1 * TSTR + lx1;
    return c;
}

template <bool BORDER>
__device__ __forceinline__ void run_tile(
    const float* __restrict__ x, const float* __restrict__ tg,
    const float* __restrict__ sg, float* __restrict__ out,
    float (&lds)[5][TD * TSTR])
{
#pragma clang fp contract(off)
    const int tx0 = blockIdx.x * TS, ty0 = blockIdx.y * TS;
    const int b = blockIdx.z;
    const int tid = threadIdx.x;          // 0..255

    const float* xp  = x  + (size_t)b * Cc * HWp;
    const float* txp = tg + (size_t)b * 2 * HWp;
    const float* planes[5] = { xp, xp + HWp, xp + 2 * HWp, txp, txp + HWp };
    const int ox = tx0 - HALO, oy = ty0 - HALO;

    // ---- uniform per-block kernel weights (overlap staging latency)
    float sig = sg[b];
    float half_width = 2.0f * sig;
    float two_sigma2 = (2.0f * sig) * sig;
    const float stepf = (float)(1.0 / 0.3333);
    float kv[4];
#pragma unroll
    for (int it = 0; it < 4; ++it) {
        float r = ((float)it + 1.0f) * stepf;
        float k = expf(-(r * r) / two_sigma2);
        kv[it] = (r < half_width) ? k : 0.0f;
    }
    const float k0 = kv[0], k1 = kv[1], k2 = kv[2], k3 = kv[3];
    // ks-nonzero is a prefix (exp never 0; r<half_width monotone shut-off).
    // readfirstlane forces SGPR => s_cbranch, not if-conversion.
    const int nlive = __builtin_amdgcn_readfirstlane(
        (k0 != 0.0f) + (k1 != 0.0f) + (k2 != 0.0f) + (k3 != 0.0f));

    // ---- stage 28x28 x 5 scalar planes into LDS
    for (int e = tid; e < TD * TD; e += 256) {
        int r = e / TD, cc = e - r * TD;
        int gy = oy + r, gx = ox + cc;
        if (BORDER) {
            gy = min(max(gy, 0), Hh - 1);
            gx = min(max(gx, 0), Ww - 1);
        }
        int g = gy * Ww + gx;
#pragma unroll
        for (int pl = 0; pl < 5; ++pl)
            lds[pl][r * TSTR + cc] = planes[pl][g];
    }
    __syncthreads();

    // ---- per-pixel march, positions in PIXEL units (exact x1024 rescale)
    const int lx = tid & (TS - 1), ly = tid >> 4;
    const int j = tx0 + lx, i = ty0 + ly;
    const int ctr = (HALO + ly) * TSTR + (HALO + lx);

    const float psx = (float)j + 0.5f;
    const float psy = (float)i + 0.5f;

    const float v0x = lds[3][ctr];
    const float v0y = lds[4][ctr];

    // two independent chains: A = +v0, B = -v0 (manually interleaved)
    float pxA = psx + v0x, pyA = psy + v0y, vxA = v0x, vyA = v0y;
    float pxB = psx - v0x, pyB = psy - v0y, vxB = -v0x, vyB = -v0y;
    float aA0 = 0.f, aA1 = 0.f, aA2 = 0.f, asA = 0.f;
    float aB0 = 0.f, aB1 = 0.f, aB2 = 0.f, asB = 0.f;

#define MKC(C, PX, PY)                                                      \
    Corn C = BORDER ? mkcorn_bor(PX, PY, ox, oy)                            \
                    : mkcorn_int(PX, PY, ox, oy)

    // color: product weights shared by 3 planes, fmaf tree (value path only;
    // trajectories unaffected). inb uses PRE-advance position.
#define COLORSTEP(C, PX, PY, KW, A0, A1, A2, AS) do {                       \
    float w_ = (KW);                                                        \
    if (BORDER) {                                                           \
        bool inb_ = ((PX) >= 0.0f) && ((PX) < 1024.0f) &&                   \
                    ((PY) >= 0.0f) && ((PY) < 1024.0f);                     \
        w_ = inb_ ? w_ : 0.0f;                                              \
    }                                                                       \
    float w00_ = C.omx * C.omy, w01_ = C.wx * C.omy;                        \
    float w10_ = C.omx * C.wy,  w11_ = C.wx * C.wy;                         \
    float s0_ = fmaf(w01_, lds[0][C.o01], w00_ * lds[0][C.o00]);            \
    s0_ = fmaf(w10_, lds[0][C.o10], s0_);                                   \
    s0_ = fmaf(w11_, lds[0][C.o11], s0_);                                   \
    A0 = fmaf(s0_, w_, A0);                                                 \
    float s1_ = fmaf(w01_, lds[1][C.o01], w00_ * lds[1][C.o00]);            \
    s1_ = fmaf(w10_, lds[1][C.o10], s1_);                                   \
    s1_ = fmaf(w11_, lds[1][C.o11], s1_);                                   \
    A1 = fmaf(s1_, w_, A1);                                                 \
    float s2_ = fmaf(w01_, lds[2][C.o01], w00_ * lds[2][C.o00]);            \
    s2_ = fmaf(w10_, lds[2][C.o10], s2_);                                   \
    s2_ = fmaf(w11_, lds[2][C.o11], s2_);                                   \
    A2 = fmaf(s2_, w_, A2);                                                 \
    AS += w_;                                                               \
} while (0)

    // tangent advance: contract-off (function-scope pragma), bit-identical
#define ADVSTEP(C, PX, PY, VX, VY) do {                                     \
    float x00_ = lds[3][C.o00], x01_ = lds[3][C.o01];                       \
    float x10_ = lds[3][C.o10], x11_ = lds[3][C.o11];                       \
    float y00_ = lds[4][C.o00], y01_ = lds[4][C.o01];                       \
    float y10_ = lds[4][C.o10], y11_ = lds[4][C.o11];                       \
    float xt_ = x00_ * C.omx + x01_ * C.wx;                                 \
    float xb_ = x10_ * C.omx + x11_ * C.wx;                                 \
    float tfx_ = xt_ * C.omy + xb_ * C.wy;                                  \
    float yt_ = y00_ * C.omx + y01_ * C.wx;                                 \
    float yb_ = y10_ * C.omx + y11_ * C.wx;                                 \
    float tfy_ = yt_ * C.omy + yb_ * C.wy;                                  \
    float vt_ = ((VX) * tfx_) + ((VY) * tfy_);                              \
    if (vt_ < 0.0f) { tfx_ = -tfx_; tfy_ = -tfy_; }                         \
    PX = (PX) + tfx_;  PY = (PY) + tfy_;                                    \
    VX = tfx_;  VY = tfy_;                                                  \
} while (0)

    if (nlive >= 1) {
        MKC(cA0, pxA, pyA);  MKC(cB0, pxB, pyB);
        COLORSTEP(cA0, pxA, pyA, k0, aA0, aA1, aA2, asA);
        COLORSTEP(cB0, pxB, pyB, k0, aB0, aB1, aB2, asB);
        if (nlive >= 2) {
            ADVSTEP(cA0, pxA, pyA, vxA, vyA);
            ADVSTEP(cB0, pxB, pyB, vxB, vyB);
            MKC(cA1, pxA, pyA);  MKC(cB1, pxB, pyB);
            COLORSTEP(cA1, pxA, pyA, k1, aA0, aA1, aA2, asA);
            COLORSTEP(cB1, pxB, pyB, k1, aB0, aB1, aB2, asB);
            if (nlive >= 3) {
                ADVSTEP(cA1, pxA, pyA, vxA, vyA);
                ADVSTEP(cB1, pxB, pyB, vxB, vyB);
                MKC(cA2, pxA, pyA);  MKC(cB2, pxB, pyB);
                COLORSTEP(cA2, pxA, pyA, k2, aA0, aA1, aA2, asA);
                COLORSTEP(cB2, pxB, pyB, k2, aB0, aB1, aB2, asB);
                if (nlive >= 4) {
                    ADVSTEP(cA2, pxA, pyA, vxA, vyA);
                    ADVSTEP(cB2, pxB, pyB, vxB, vyB);
                    MKC(cA3, pxA, pyA);  MKC(cB3, pxB, pyB);
                    COLORSTEP(cA3, pxA, pyA, k3, aA0, aA1, aA2, asA);
                    COLORSTEP(cB3, pxB, pyB, k3, aB0, aB1, aB2, asB);
                }
            }
        }
    }
#undef MKC
#undef COLORSTEP
#undef ADVSTEP

    const int pix = i * Ww + j;
    float xc0 = lds[0][ctr], xc1 = lds[1][ctr], xc2 = lds[2][ctr];
    float denom = (1.0f + asA) + asB;
    float* op = out + (size_t)b * Cc * HWp;
    op[pix]           = ((xc0 + aA0) + aB0) / denom;
    op[pix + HWp]     = ((xc1 + aA1) + aB1) / denom;
    op[pix + 2 * HWp] = ((xc2 + aA2) + aB2) / denom;
}

__global__ __launch_bounds__(256, 8) void flow_smooth_kernel(
    const float* __restrict__ x,
    const float* __restrict__ tg,
    const float* __restrict__ sg,
    float* __restrict__ out)
{
    __shared__ float lds[5][TD * TSTR];   // 16.2 KB
    const bool border = (blockIdx.x == 0) || (blockIdx.x == gridDim.x - 1) ||
                        (blockIdx.y == 0) || (blockIdx.y == gridDim.y - 1);
    if (border) run_tile<true >(x, tg, sg, out, lds);
    else        run_tile<false>(x, tg, sg, out, lds);
}

extern "C" void kernel_launch(void* const* d_in, const int* in_sizes, int n_in,
                              void* d_out, int out_size, void* d_ws, size_t ws_size,
                              hipStream_t stream) {
    const float* x = nullptr; const float* tg = nullptr; const float* sg = nullptr;
    for (int t = 0; t < n_in; ++t) {
        if (in_sizes[t] == Bb * Cc * HWp)      x  = (const float*)d_in[t];
        else if (in_sizes[t] == Bb * 2 * HWp)  tg = (const float*)d_in[t];
        else                                   sg = (const float*)d_in[t];
    }
    float* out = (float*)d_out;

    dim3 block(256, 1, 1);
    dim3 grid(Ww / TS, Hh / TS, Bb);   // 64 x 64 x 2 = 8192 blocks
    flow_smooth_kernel<<<grid, block, 0, stream>>>(x, tg, sg, out);
}

// Round 5
// 115.488 us; speedup vs baseline: 1.1330x; 1.0672x over previous
//
#include <hip/hip_runtime.h>

// B=2, C=3, H=W=1024, fp32. History: R12 56.1us; R13 float4-pack regressed;
// R14/R15 53.5us -- conflicts pinned at 1.478e7 across R12/14/15 = cost of
// the LIVE 104 gather words (guards always branched via execz). 17.3 extra
// cy per read2 (ideal 4) => STRUCTURED conflicts: with TSTR=29 == -3 mod 32,
// a wave's 4 16-lane row-combs stack into a 25-bank window (banks 14-20 get
// 4 rows, banks 30-4 get none).
// R16: bank-comb layout fix. Tile 32x8 (lx=tid&31: each row spans all 32
// banks) + TSTR=48 == 16 mod 32 (row-to-row bank shift 16): a 64-lane access
// = 2 rows covering every bank exactly 2x (free). Per-lane drift adds
// 16*dy+dx -- a near-permutation displacement at every step, not a pile-up.
// LDS 5x20x48x4 = 19.2KB -> still 8 blocks/CU. Interior staging as aligned
// float2 (ox even). March arithmetic/order/clamps untouched => absmax must
// remain exactly 0.00390625.
constexpr int Bb = 2, Cc = 3, Hh = 1024, Ww = 1024;
constexpr int HWp = Hh * Ww;
constexpr int TSX = 32, TSY = 8;        // tile 32x8, 256 threads
constexpr int HALO = 6;                 // >= max drift 4.5 + margin
constexpr int TDX = TSX + 2 * HALO;     // 44
constexpr int TDY = TSY + 2 * HALO;     // 20
constexpr int TSTR = 48;                // row stride == 16 mod 32: bank comb

struct Corn { int o00, o01, o10, o11; float wx, wy, omx, omy; };

// Interior: pixel-space positions, never clamps (drift bound |dp|<=4.5px).
__device__ __forceinline__ Corn mkcorn_int(float px, float py, int ox, int oy) {
#pragma clang fp contract(off)
    float fx = px - 0.5f;
    float fy = py - 0.5f;
    float fx0 = floorf(fx), fy0 = floorf(fy);
    Corn c;
    c.wx = fx - fx0;  c.wy = fy - fy0;
    c.omx = 1.0f - c.wx;  c.omy = 1.0f - c.wy;
    int o = ((int)fy0 - oy) * TSTR + ((int)fx0 - ox);
    c.o00 = o;        c.o01 = o + 1;          // read2-mergeable pairs
    c.o10 = o + TSTR; c.o11 = o + TSTR + 1;
    return c;
}

// Border: full clamp logic, arithmetic identical to R12.
__device__ __forceinline__ Corn mkcorn_bor(float px, float py, int ox, int oy) {
#pragma clang fp contract(off)
    float fx = px - 0.5f;
    float fy = py - 0.5f;
    float fx0 = floorf(fx), fy0 = floorf(fy);
    Corn c;
    c.wx = fx - fx0;  c.wy = fy - fy0;
    c.omx = 1.0f - c.wx;  c.omy = 1.0f - c.wy;
    int x0 = (int)fx0, y0 = (int)fy0;
    int x0i = min(max(x0, 0), Ww - 1);
    int x1i = min(x0i + 1, Ww - 1);
    int y0i = min(max(y0, 0), Hh - 1);
    int y1i = min(y0i + 1, Hh - 1);
    int lx0 = x0i - ox, lx1 = x1i - ox;
    int ly0 = y0i - oy, ly1 = y1i - oy;
    c.o00 = ly0 * TSTR + lx0;  c.o01 = ly0 * TSTR + lx1;
    c.o10 = ly1 * TSTR + lx0;  c.o11 = ly1 * TSTR + lx1;
    return c;
}

template <bool BORDER>
__device__ __forceinline__ void run_tile(
    const float* __restrict__ x, const float* __restrict__ tg,
    const float* __restrict__ sg, float* __restrict__ out,
    float (&lds)[5][TDY * TSTR])
{
#pragma clang fp contract(off)
    const int tx0 = blockIdx.x * TSX, ty0 = blockIdx.y * TSY;
    const int b = blockIdx.z;
    const int tid = threadIdx.x;          // 0..255

    const float* xp  = x  + (size_t)b * Cc * HWp;
    const float* txp = tg + (size_t)b * 2 * HWp;
    const float* planes[5] = { xp, xp + HWp, xp + 2 * HWp, txp, txp + HWp };
    const int ox = tx0 - HALO, oy = ty0 - HALO;

    // ---- uniform per-block kernel weights (overlap staging latency)
    float sig = sg[b];
    float half_width = 2.0f * sig;
    float two_sigma2 = (2.0f * sig) * sig;
    const float stepf = (float)(1.0 / 0.3333);
    float kv[4];
#pragma unroll
    for (int it = 0; it < 4; ++it) {
        float r = ((float)it + 1.0f) * stepf;
        float k = expf(-(r * r) / two_sigma2);
        kv[it] = (r < half_width) ? k : 0.0f;
    }
    const float k0 = kv[0], k1 = kv[1], k2 = kv[2], k3 = kv[3];
    // ks-nonzero is a prefix (exp never 0; r<half_width monotone shut-off).
    const int nlive = __builtin_amdgcn_readfirstlane(
        (k0 != 0.0f) + (k1 != 0.0f) + (k2 != 0.0f) + (k3 != 0.0f));

    // ---- stage 20x44 x 5 planes into LDS
    if (!BORDER) {
        // interior: ox is even (tx0 = 32k, HALO = 6) => float2 aligned
        for (int e = tid; e < TDY * (TDX / 2); e += 256) {
            int r = e / (TDX / 2);
            int c2 = e - r * (TDX / 2);
            int g = (oy + r) * Ww + ox + 2 * c2;
            int d = r * TSTR + 2 * c2;
#pragma unroll
            for (int pl = 0; pl < 5; ++pl) {
                float2 v = *reinterpret_cast<const float2*>(planes[pl] + g);
                *reinterpret_cast<float2*>(&lds[pl][d]) = v;
            }
        }
    } else {
        for (int e = tid; e < TDY * TDX; e += 256) {
            int r = e / TDX, cc = e - r * TDX;
            int gy = min(max(oy + r, 0), Hh - 1);
            int gx = min(max(ox + cc, 0), Ww - 1);
            int g = gy * Ww + gx;
#pragma unroll
            for (int pl = 0; pl < 5; ++pl)
                lds[pl][r * TSTR + cc] = planes[pl][g];
        }
    }
    __syncthreads();

    // ---- per-pixel march, positions in PIXEL units (exact x1024 rescale)
    const int lx = tid & (TSX - 1), ly = tid >> 5;   // 32x8
    const int j = tx0 + lx, i = ty0 + ly;
    const int ctr = (HALO + ly) * TSTR + (HALO + lx);

    const float psx = (float)j + 0.5f;
    const float psy = (float)i + 0.5f;

    const float v0x = lds[3][ctr];
    const float v0y = lds[4][ctr];

    // two independent chains: A = +v0, B = -v0 (manually interleaved)
    float pxA = psx + v0x, pyA = psy + v0y, vxA = v0x, vyA = v0y;
    float pxB = psx - v0x, pyB = psy - v0y, vxB = -v0x, vyB = -v0y;
    float aA0 = 0.f, aA1 = 0.f, aA2 = 0.f, asA = 0.f;
    float aB0 = 0.f, aB1 = 0.f, aB2 = 0.f, asB = 0.f;

#define MKC(C, PX, PY)                                                      \
    Corn C = BORDER ? mkcorn_bor(PX, PY, ox, oy)                            \
                    : mkcorn_int(PX, PY, ox, oy)

#define COLORSTEP(C, PX, PY, KW, A0, A1, A2, AS) do {                       \
    float w_ = (KW);                                                        \
    if (BORDER) {                                                           \
        bool inb_ = ((PX) >= 0.0f) && ((PX) < 1024.0f) &&                   \
                    ((PY) >= 0.0f) && ((PY) < 1024.0f);                     \
        w_ = inb_ ? w_ : 0.0f;                                              \
    }                                                                       \
    float w00_ = C.omx * C.omy, w01_ = C.wx * C.omy;                        \
    float w10_ = C.omx * C.wy,  w11_ = C.wx * C.wy;                         \
    float s0_ = fmaf(w01_, lds[0][C.o01], w00_ * lds[0][C.o00]);            \
    s0_ = fmaf(w10_, lds[0][C.o10], s0_);                                   \
    s0_ = fmaf(w11_, lds[0][C.o11], s0_);                                   \
    A0 = fmaf(s0_, w_, A0);                                                 \
    float s1_ = fmaf(w01_, lds[1][C.o01], w00_ * lds[1][C.o00]);            \
    s1_ = fmaf(w10_, lds[1][C.o10], s1_);                                   \
    s1_ = fmaf(w11_, lds[1][C.o11], s1_);                                   \
    A1 = fmaf(s1_, w_, A1);                                                 \
    float s2_ = fmaf(w01_, lds[2][C.o01], w00_ * lds[2][C.o00]);            \
    s2_ = fmaf(w10_, lds[2][C.o10], s2_);                                   \
    s2_ = fmaf(w11_, lds[2][C.o11], s2_);                                   \
    A2 = fmaf(s2_, w_, A2);                                                 \
    AS += w_;                                                               \
} while (0)

    // tangent advance: contract-off (function-scope pragma), bit-identical
#define ADVSTEP(C, PX, PY, VX, VY) do {                                     \
    float x00_ = lds[3][C.o00], x01_ = lds[3][C.o01];                       \
    float x10_ = lds[3][C.o10], x11_ = lds[3][C.o11];                       \
    float y00_ = lds[4][C.o00], y01_ = lds[4][C.o01];                       \
    float y10_ = lds[4][C.o10], y11_ = lds[4][C.o11];                       \
    float xt_ = x00_ * C.omx + x01_ * C.wx;                                 \
    float xb_ = x10_ * C.omx + x11_ * C.wx;                                 \
    float tfx_ = xt_ * C.omy + xb_ * C.wy;                                  \
    float yt_ = y00_ * C.omx + y01_ * C.wx;                                 \
    float yb_ = y10_ * C.omx + y11_ * C.wx;                                 \
    float tfy_ = yt_ * C.omy + yb_ * C.wy;                                  \
    float vt_ = ((VX) * tfx_) + ((VY) * tfy_);                              \
    if (vt_ < 0.0f) { tfx_ = -tfx_; tfy_ = -tfy_; }                         \
    PX = (PX) + tfx_;  PY = (PY) + tfy_;                                    \
    VX = tfx_;  VY = tfy_;                                                  \
} while (0)

    if (nlive >= 1) {
        MKC(cA0, pxA, pyA);  MKC(cB0, pxB, pyB);
        COLORSTEP(cA0, pxA, pyA, k0, aA0, aA1, aA2, asA);
        COLORSTEP(cB0, pxB, pyB, k0, aB0, aB1, aB2, asB);
        if (nlive >= 2) {
            ADVSTEP(cA0, pxA, pyA, vxA, vyA);
            ADVSTEP(cB0, pxB, pyB, vxB, vyB);
            MKC(cA1, pxA, pyA);  MKC(cB1, pxB, pyB);
            COLORSTEP(cA1, pxA, pyA, k1, aA0, aA1, aA2, asA);
            COLORSTEP(cB1, pxB, pyB, k1, aB0, aB1, aB2, asB);
            if (nlive >= 3) {
                ADVSTEP(cA1, pxA, pyA, vxA, vyA);
                ADVSTEP(cB1, pxB, pyB, vxB, vyB);
                MKC(cA2, pxA, pyA);  MKC(cB2, pxB, pyB);
                COLORSTEP(cA2, pxA, pyA, k2, aA0, aA1, aA2, asA);
                COLORSTEP(cB2, pxB, pyB, k2, aB0, aB1, aB2, asB);
                if (nlive >= 4) {
                    ADVSTEP(cA2, pxA, pyA, vxA, vyA);
                    ADVSTEP(cB2, pxB, pyB, vxB, vyB);
                    MKC(cA3, pxA, pyA);  MKC(cB3, pxB, pyB);
                    COLORSTEP(cA3, pxA, pyA, k3, aA0, aA1, aA2, asA);
                    COLORSTEP(cB3, pxB, pyB, k3, aB0, aB1, aB2, asB);
                }
            }
        }
    }
#undef MKC
#undef COLORSTEP
#undef ADVSTEP

    const int pix = i * Ww + j;
    float xc0 = lds[0][ctr], xc1 = lds[1][ctr], xc2 = lds[2][ctr];
    float denom = (1.0f + asA) + asB;
    float* op = out + (size_t)b * Cc * HWp;
    op[pix]           = ((xc0 + aA0) + aB0) / denom;
    op[pix + HWp]     = ((xc1 + aA1) + aB1) / denom;
    op[pix + 2 * HWp] = ((xc2 + aA2) + aB2) / denom;
}

__global__ __launch_bounds__(256, 8) void flow_smooth_kernel(
    const float* __restrict__ x,
    const float* __restrict__ tg,
    const float* __restrict__ sg,
    float* __restrict__ out)
{
    __shared__ float lds[5][TDY * TSTR];   // 5 x 960 x 4B = 19.2 KB
    const bool border = (blockIdx.x == 0) || (blockIdx.x == gridDim.x - 1) ||
                        (blockIdx.y == 0) || (blockIdx.y == gridDim.y - 1);
    if (border) run_tile<true >(x, tg, sg, out, lds);
    else        run_tile<false>(x, tg, sg, out, lds);
}

extern "C" void kernel_launch(void* const* d_in, const int* in_sizes, int n_in,
                              void* d_out, int out_size, void* d_ws, size_t ws_size,
                              hipStream_t stream) {
    const float* x = nullptr; const float* tg = nullptr; const float* sg = nullptr;
    for (int t = 0; t < n_in; ++t) {
        if (in_sizes[t] == Bb * Cc * HWp)      x  = (const float*)d_in[t];
        else if (in_sizes[t] == Bb * 2 * HWp)  tg = (const float*)d_in[t];
        else                                   sg = (const float*)d_in[t];
    }
    float* out = (float*)d_out;

    dim3 block(256, 1, 1);
    dim3 grid(Ww / TSX, Hh / TSY, Bb);   // 32 x 128 x 2 = 8192 blocks
    flow_smooth_kernel<<<grid, block, 0, stream>>>(x, tg, sg, out);
}